// Round 1
// baseline (1217.366 us; speedup 1.0000x reference)
//
#include <hip/hip_runtime.h>
#include <math.h>

#define B_    8
#define CIN_  128
#define H_    128
#define W_    128
#define NPIX_ 16384
#define G_    8

// branch pool target sizes (h, w)
__device__ __constant__ int c_oh[4] = {1, 11, 3, 5};
__device__ __constant__ int c_ow[4] = {11, 1, 5, 3};
// bin-count prefix: 0, 11, 22, 37, 52

// ---------------------------------------------------------------------------
// Kernel 1: adaptive avg pool, 4 branches, one block per (b, c) image.
// p layout: p[(br*1024 + bc)*16 + bin]  (bin = ih*ow + iw, row-major)
// ---------------------------------------------------------------------------
__global__ void pool_kernel(const float* __restrict__ x, float* __restrict__ p)
{
    int bc = blockIdx.x;                       // b*128 + c
    const float* img = x + (size_t)bc * NPIX_;
    int wv = threadIdx.x >> 6, lane = threadIdx.x & 63;
    int nwaves = blockDim.x >> 6;
    for (int bin = wv; bin < 52; bin += nwaves) {
        int br, loc;
        if (bin < 11)      { br = 0; loc = bin; }
        else if (bin < 22) { br = 1; loc = bin - 11; }
        else if (bin < 37) { br = 2; loc = bin - 22; }
        else               { br = 3; loc = bin - 37; }
        int oh = c_oh[br], ow = c_ow[br];
        int ih = loc / ow, iw = loc % ow;
        int hs = (ih * H_) / oh, he = ((ih + 1) * H_ + oh - 1) / oh;
        int ws2 = (iw * W_) / ow, we = ((iw + 1) * W_ + ow - 1) / ow;
        int nh = he - hs, nwd = we - ws2, tot = nh * nwd;
        float s = 0.f;
        for (int t = lane; t < tot; t += 64) {
            int r = t / nwd, c2 = t - r * nwd;
            s += img[(hs + r) * W_ + ws2 + c2];
        }
        #pragma unroll
        for (int off = 32; off > 0; off >>= 1) s += __shfl_down(s, off);
        if (lane == 0) p[(br * 1024 + bc) * 16 + loc] = s / (float)tot;
    }
}

// ---------------------------------------------------------------------------
// Kernel 2: per-(b,c) tiny matmul  q[m] = sum_k Wl[m,k] * p[k] + bl[m]
// q layout identical to p.
// ---------------------------------------------------------------------------
__global__ void qmat_kernel(const float* __restrict__ p, float* __restrict__ q,
                            const float* __restrict__ W0, const float* __restrict__ b0,
                            const float* __restrict__ W1, const float* __restrict__ b1,
                            const float* __restrict__ W2, const float* __restrict__ b2,
                            const float* __restrict__ W3, const float* __restrict__ b3)
{
    int bc = blockIdx.x;
    int t = threadIdx.x;
    if (t >= 52) return;
    int br, m;
    if (t < 11)      { br = 0; m = t; }
    else if (t < 22) { br = 1; m = t - 11; }
    else if (t < 37) { br = 2; m = t - 22; }
    else             { br = 3; m = t - 37; }
    int cdim = (br < 2) ? 11 : 15;
    const float* Wl; const float* bl;
    if (br == 0)      { Wl = W0; bl = b0; }
    else if (br == 1) { Wl = W1; bl = b1; }
    else if (br == 2) { Wl = W2; bl = b2; }
    else              { Wl = W3; bl = b3; }
    const float* pr = p + (br * 1024 + bc) * 16;
    float acc = bl[m];
    for (int k = 0; k < cdim; ++k) acc += Wl[m * cdim + k] * pr[k];
    q[(br * 1024 + bc) * 16 + m] = acc;
}

// ---------------------------------------------------------------------------
// Kernel 3: fused center-conv + interp + merge + GRU.
// One thread per pixel, loop over the 8 GRU groups; per-group weights in LDS.
// ---------------------------------------------------------------------------
__global__ __launch_bounds__(256, 2) void fused_kernel(
    const float* __restrict__ x, const float* __restrict__ q,
    const float* __restrict__ Wc, const float* __restrict__ Wm,
    const float* __restrict__ Wih, const float* __restrict__ Whh,
    const float* __restrict__ bih, const float* __restrict__ bhh,
    float* __restrict__ out)
{
    __shared__ float s_q[4 * 2048];   // 32 KB: q for this b, rows padded to 16
    __shared__ float s_wm[1024];      // 4 KB : W_merge [g][o*4+i]
    __shared__ float s_wc[512];       // 2 KB : W_center for current group
    __shared__ float s_ih[3072];      // 12 KB: Wih for current group
    __shared__ float s_hh[3072];      // 12 KB: Whh for current group
    __shared__ float s_bi[96], s_bh[96];

    int tid = threadIdx.x;
    int b   = blockIdx.x >> 6;                  // 64 blocks per batch
    int pix = ((blockIdx.x & 63) << 8) + tid;   // 0..16383
    int h = pix >> 7, w = pix & 127;

    // stage q (all 4 branches for this b) and W_merge once
    for (int i = tid; i < 8192; i += 256) {
        int br = i >> 11, rest = i & 2047;
        s_q[i] = q[((br * 1024 + b * 128) << 4) + rest];
    }
    for (int i = tid; i < 1024; i += 256) s_wm[i] = Wm[i];

    const float* xb = x + (size_t)b * CIN_ * NPIX_ + pix;
    float* ob = out + (size_t)b * 256 * NPIX_ + pix;

    for (int gg = 0; gg < 8; ++gg) {
        __syncthreads();   // also covers initial q staging
        for (int i = tid; i < 512; i += 256) s_wc[i] = Wc[gg * 512 + i];
        for (int i = tid; i < 3072; i += 256) {
            s_ih[i] = Wih[gg * 3072 + i];
            s_hh[i] = Whh[gg * 3072 + i];
        }
        if (tid < 96) { s_bi[tid] = bih[gg * 96 + tid]; s_bh[tid] = bhh[gg * 96 + tid]; }
        __syncthreads();

        // ---- center conv: cg[32] = W_center[gg] (32x16) @ x[b, 16gg..16gg+16, pix]
        float xv[16];
        #pragma unroll
        for (int ci = 0; ci < 16; ++ci)
            xv[ci] = xb[(size_t)(gg * 16 + ci) * NPIX_];
        float cg[32];
        #pragma unroll
        for (int o = 0; o < 32; ++o) {
            float acc = 0.f;
            #pragma unroll
            for (int ci = 0; ci < 16; ++ci) acc += s_wc[o * 16 + ci] * xv[ci];
            cg[o] = acc;
        }

        // ---- bilinear taps (align_corners=True) for branch br = gg>>1
        int br = gg >> 1;
        int oh = c_oh[br], ow = c_ow[br];
        int i0h = 0, i1h = 0; float fh = 0.f;
        if (oh > 1) {
            float src = (float)(h * (oh - 1)) / 127.f;
            i0h = (int)src;
            if (i0h > oh - 2) i0h = oh - 2;
            fh = src - (float)i0h;
            i1h = i0h + 1;
        }
        int i0w = 0, i1w = 0; float fw = 0.f;
        if (ow > 1) {
            float src = (float)(w * (ow - 1)) / 127.f;
            i0w = (int)src;
            if (i0w > ow - 2) i0w = ow - 2;
            fw = src - (float)i0w;
            i1w = i0w + 1;
        }
        int t0 = i0h * ow + i0w, t1 = i0h * ow + i1w;
        int t2 = i1h * ow + i0w, t3 = i1h * ow + i1w;
        float wt0 = (1.f - fh) * (1.f - fw), wt1 = (1.f - fh) * fw;
        float wt2 = fh * (1.f - fw),         wt3 = fh * fw;

        // ---- interp + merge: bg[32]
        int chb = (gg & 1) * 64;                     // branch channel base
        const float* sqb = &s_q[br * 2048 + chb * 16];
        float bg[32];
        #pragma unroll
        for (int gl = 0; gl < 16; ++gl) {
            const float* qr = sqb + (4 * gl) * 16;
            float a0 = wt0 * qr[t0] + wt1 * qr[t1] + wt2 * qr[t2] + wt3 * qr[t3]; qr += 16;
            float a1 = wt0 * qr[t0] + wt1 * qr[t1] + wt2 * qr[t2] + wt3 * qr[t3]; qr += 16;
            float a2 = wt0 * qr[t0] + wt1 * qr[t1] + wt2 * qr[t2] + wt3 * qr[t3]; qr += 16;
            float a3 = wt0 * qr[t0] + wt1 * qr[t1] + wt2 * qr[t2] + wt3 * qr[t3];
            const float* wm = &s_wm[(16 * gg + gl) * 8];
            bg[2 * gl]     = wm[0] * a0 + wm[1] * a1 + wm[2] * a2 + wm[3] * a3;
            bg[2 * gl + 1] = wm[4] * a0 + wm[5] * a1 + wm[6] * a2 + wm[7] * a3;
        }

        // ---- GRU cell, output channel = hid*8 + gg
        #pragma unroll 2
        for (int hh2 = 0; hh2 < 32; ++hh2) {
            float ar = s_bi[hh2], az = s_bi[hh2 + 32], an = s_bi[hh2 + 64];
            float hr = s_bh[hh2], hz = s_bh[hh2 + 32], hn = s_bh[hh2 + 64];
            const float* wr_i = &s_ih[hh2 * 32];
            const float* wz_i = &s_ih[(hh2 + 32) * 32];
            const float* wn_i = &s_ih[(hh2 + 64) * 32];
            const float* wr_h = &s_hh[hh2 * 32];
            const float* wz_h = &s_hh[(hh2 + 32) * 32];
            const float* wn_h = &s_hh[(hh2 + 64) * 32];
            #pragma unroll
            for (int k = 0; k < 32; ++k) {
                ar += wr_i[k] * bg[k];
                az += wz_i[k] * bg[k];
                an += wn_i[k] * bg[k];
                hr += wr_h[k] * cg[k];
                hz += wz_h[k] * cg[k];
                hn += wn_h[k] * cg[k];
            }
            float r = 1.f / (1.f + __expf(-(ar + hr)));
            float z = 1.f / (1.f + __expf(-(az + hz)));
            float e2 = __expf(2.f * (an + r * hn));
            float n = (e2 - 1.f) / (e2 + 1.f);
            float y = (1.f - z) * n + z * cg[hh2];
            ob[(size_t)((hh2 << 3) + gg) * NPIX_] = y;
        }
    }
}

// ---------------------------------------------------------------------------
extern "C" void kernel_launch(void* const* d_in, const int* in_sizes, int n_in,
                              void* d_out, int out_size, void* d_ws, size_t ws_size,
                              hipStream_t stream)
{
    const float* x   = (const float*)d_in[0];
    const float* Wc  = (const float*)d_in[1];
    const float* W0  = (const float*)d_in[2];
    const float* b0  = (const float*)d_in[3];
    const float* W1  = (const float*)d_in[4];
    const float* b1  = (const float*)d_in[5];
    const float* W2  = (const float*)d_in[6];
    const float* b2  = (const float*)d_in[7];
    const float* W3  = (const float*)d_in[8];
    const float* b3  = (const float*)d_in[9];
    const float* Wm  = (const float*)d_in[10];
    const float* Wih = (const float*)d_in[11];
    const float* Whh = (const float*)d_in[12];
    const float* bih = (const float*)d_in[13];
    const float* bhh = (const float*)d_in[14];
    float* out = (float*)d_out;

    float* p = (float*)d_ws;              // 4*1024*16 floats = 256 KB
    float* q = p + 4 * 1024 * 16;         // another 256 KB

    pool_kernel<<<1024, 256, 0, stream>>>(x, p);
    qmat_kernel<<<1024, 64, 0, stream>>>(p, q, W0, b0, W1, b1, W2, b2, W3, b3);
    fused_kernel<<<512, 256, 0, stream>>>(x, q, Wc, Wm, Wih, Whh, bih, bhh, out);
}

// Round 2
// 618.217 us; speedup vs baseline: 1.9692x; 1.9692x over previous
//
#include <hip/hip_runtime.h>
#include <math.h>

#define B_    8
#define CIN_  128
#define H_    128
#define W_    128
#define NPIX_ 16384

// branch pool target sizes (h, w) and w-bin offsets into the 20-bin row table
__device__ __constant__ int c_oh[4]   = {1, 11, 3, 5};
__device__ __constant__ int c_ow[4]   = {11, 1, 5, 3};
__device__ __constant__ int c_woff[4] = {0, 11, 12, 17};

// ---------------------------------------------------------------------------
// Kernel 1: adaptive avg pool, single coalesced pass over x.
// One block per (b,c). Stage 32 rows at a time in LDS; compute the 20 w-bin
// row sums (static bounds per bin); then h-reduce into the 52 output bins.
// p layout: p[(br*1024 + bc)*16 + (ih*ow+iw)]
// ---------------------------------------------------------------------------
__global__ __launch_bounds__(256) void pool_kernel(const float* __restrict__ x,
                                                   float* __restrict__ p)
{
    __shared__ float s_img[32][129];   // 16.5 KB, +1 pad: conflict-free row reads
    __shared__ float s_rb[128][20];    // 10 KB: per-row w-bin sums

    int bc = blockIdx.x;               // b*128 + c
    const float* img = x + (size_t)bc * NPIX_;
    int t = threadIdx.x;

    for (int pass = 0; pass < 4; ++pass) {
        // ---- stage 32 rows, coalesced float4
        #pragma unroll
        for (int i = 0; i < 4; ++i) {
            int idx = t + i * 256;            // float4 index 0..1023
            int rl = idx >> 5, c4 = idx & 31; // 32 float4 per row
            float4 v = *(const float4*)(img + ((pass * 32 + rl) << 7) + (c4 << 2));
            s_img[rl][c4 * 4 + 0] = v.x;
            s_img[rl][c4 * 4 + 1] = v.y;
            s_img[rl][c4 * 4 + 2] = v.z;
            s_img[rl][c4 * 4 + 3] = v.w;
        }
        __syncthreads();
        // ---- 640 tasks: (wbin j 0..19) x (row_local 0..31); scalar acc only
        for (int task = t; task < 640; task += 256) {
            int j = task >> 5, rl = task & 31;
            int br, iw;
            if (j < 11)      { br = 0; iw = j; }
            else if (j < 12) { br = 1; iw = 0; }
            else if (j < 17) { br = 2; iw = j - 12; }
            else             { br = 3; iw = j - 17; }
            int ow = c_ow[br];
            int ws = (iw * W_) / ow, we = ((iw + 1) * W_ + ow - 1) / ow;
            float s = 0.f;
            for (int c = ws; c < we; ++c) s += s_img[rl][c];
            s_rb[pass * 32 + rl][j] = s;
        }
        __syncthreads();
    }

    // ---- h-reduction into 52 output bins
    if (t < 52) {
        int br, loc;
        if (t < 11)      { br = 0; loc = t; }
        else if (t < 22) { br = 1; loc = t - 11; }
        else if (t < 37) { br = 2; loc = t - 22; }
        else             { br = 3; loc = t - 37; }
        int oh = c_oh[br], ow = c_ow[br];
        int ih = loc / ow, iw = loc % ow;
        int hs = (ih * H_) / oh, he = ((ih + 1) * H_ + oh - 1) / oh;
        int ws = (iw * W_) / ow, we = ((iw + 1) * W_ + ow - 1) / ow;
        int j = c_woff[br] + iw;
        float s = 0.f;
        for (int r = hs; r < he; ++r) s += s_rb[r][j];
        p[(br * 1024 + bc) * 16 + loc] = s / (float)((he - hs) * (we - ws));
    }
}

// ---------------------------------------------------------------------------
// Kernel 2: per-(b,c) tiny matmul  q[m] = sum_k Wl[m,k] * p[k] + bl[m]
// ---------------------------------------------------------------------------
__global__ void qmat_kernel(const float* __restrict__ p, float* __restrict__ q,
                            const float* __restrict__ W0, const float* __restrict__ b0,
                            const float* __restrict__ W1, const float* __restrict__ b1,
                            const float* __restrict__ W2, const float* __restrict__ b2,
                            const float* __restrict__ W3, const float* __restrict__ b3)
{
    int bc = blockIdx.x;
    int t = threadIdx.x;
    if (t >= 52) return;
    int br, m;
    if (t < 11)      { br = 0; m = t; }
    else if (t < 22) { br = 1; m = t - 11; }
    else if (t < 37) { br = 2; m = t - 22; }
    else             { br = 3; m = t - 37; }
    int cdim = (br < 2) ? 11 : 15;
    const float* Wl; const float* bl;
    if (br == 0)      { Wl = W0; bl = b0; }
    else if (br == 1) { Wl = W1; bl = b1; }
    else if (br == 2) { Wl = W2; bl = b2; }
    else              { Wl = W3; bl = b3; }
    const float* pr = p + (br * 1024 + bc) * 16;
    float acc = bl[m];
    for (int k = 0; k < cdim; ++k) acc += Wl[m * cdim + k] * pr[k];
    q[(br * 1024 + bc) * 16 + m] = acc;
}

// ---------------------------------------------------------------------------
// Kernel 3: fused center-conv + interp + merge + GRU.
// One block per (b, pixel-tile, group). All weights via wave-uniform global
// loads (compiler emits s_load -> SGPR operands); only q taps live in LDS.
// ---------------------------------------------------------------------------
__global__ __launch_bounds__(256) void fused_kernel(
    const float* __restrict__ x, const float* __restrict__ q,
    const float* __restrict__ Wc, const float* __restrict__ Wm,
    const float* __restrict__ Wih, const float* __restrict__ Whh,
    const float* __restrict__ bih, const float* __restrict__ bhh,
    float* __restrict__ out)
{
    __shared__ float s_q[1024];   // 4 KB: 64 branch-channels x 16 bins

    int bid  = blockIdx.x;
    int gg   = bid & 7;
    int tile = (bid >> 3) & 63;
    int b    = bid >> 9;
    int tid  = threadIdx.x;
    int pix  = (tile << 8) + tid;
    int h = pix >> 7, w = pix & 127;
    int br = gg >> 1, chb = (gg & 1) << 6;

    {
        int base = (br * 1024 + b * 128 + chb) << 4;
        for (int i = tid; i < 1024; i += 256) s_q[i] = q[base + i];
    }
    __syncthreads();

    // ---- center conv: cg[32] = W_center[gg] (32x16) @ x[b, 16gg.., pix]
    const float* xb = x + ((size_t)b * CIN_ + gg * 16) * NPIX_ + pix;
    float xv[16];
    #pragma unroll
    for (int ci = 0; ci < 16; ++ci) xv[ci] = xb[(size_t)ci * NPIX_];
    const float* wcg = Wc + (gg << 9);
    float cg[32];
    #pragma unroll
    for (int o = 0; o < 32; ++o) {
        float a = 0.f;
        #pragma unroll
        for (int ci = 0; ci < 16; ++ci) a = fmaf(wcg[(o << 4) + ci], xv[ci], a);
        cg[o] = a;
    }

    // ---- bilinear taps (align_corners=True) for branch br
    int oh = c_oh[br], ow = c_ow[br];
    int i0h = 0, i1h = 0; float fh = 0.f;
    if (oh > 1) {
        float src = (float)(h * (oh - 1)) / 127.f;
        i0h = (int)src;
        if (i0h > oh - 2) i0h = oh - 2;
        fh = src - (float)i0h;
        i1h = i0h + 1;
    }
    int i0w = 0, i1w = 0; float fw = 0.f;
    if (ow > 1) {
        float src = (float)(w * (ow - 1)) / 127.f;
        i0w = (int)src;
        if (i0w > ow - 2) i0w = ow - 2;
        fw = src - (float)i0w;
        i1w = i0w + 1;
    }
    int t0 = i0h * ow + i0w, t1 = i0h * ow + i1w;
    int t2 = i1h * ow + i0w, t3 = i1h * ow + i1w;
    float wt0 = (1.f - fh) * (1.f - fw), wt1 = (1.f - fh) * fw;
    float wt2 = fh * (1.f - fw),         wt3 = fh * fw;

    // ---- interp + merge: bg[32]
    const float* wm = Wm + (gg << 7);
    float bg[32];
    #pragma unroll
    for (int gl = 0; gl < 16; ++gl) {
        const float* qr = s_q + (gl << 6);
        float a0 = wt0 * qr[t0]      + wt1 * qr[t1]      + wt2 * qr[t2]      + wt3 * qr[t3];
        float a1 = wt0 * qr[t0 + 16] + wt1 * qr[t1 + 16] + wt2 * qr[t2 + 16] + wt3 * qr[t3 + 16];
        float a2 = wt0 * qr[t0 + 32] + wt1 * qr[t1 + 32] + wt2 * qr[t2 + 32] + wt3 * qr[t3 + 32];
        float a3 = wt0 * qr[t0 + 48] + wt1 * qr[t1 + 48] + wt2 * qr[t2 + 48] + wt3 * qr[t3 + 48];
        const float* wmg = wm + (gl << 3);
        bg[2 * gl]     = wmg[0] * a0 + wmg[1] * a1 + wmg[2] * a2 + wmg[3] * a3;
        bg[2 * gl + 1] = wmg[4] * a0 + wmg[5] * a1 + wmg[6] * a2 + wmg[7] * a3;
    }

    // ---- GRU cell; output channel = hid*8 + gg
    const float* wih = Wih + gg * 3072;
    const float* whh = Whh + gg * 3072;
    const float* bi  = bih + gg * 96;
    const float* bh  = bhh + gg * 96;
    float* ob = out + (size_t)b * 256 * NPIX_ + pix;

    #pragma unroll 2
    for (int hh2 = 0; hh2 < 32; ++hh2) {
        float rr = bi[hh2]      + bh[hh2];       // r-gate biases merge
        float zz = bi[hh2 + 32] + bh[hh2 + 32];  // z-gate biases merge
        float an = bi[hh2 + 64];
        float hn = bh[hh2 + 64];
        const float* wr_i = wih + (hh2 << 5);
        const float* wz_i = wih + ((hh2 + 32) << 5);
        const float* wn_i = wih + ((hh2 + 64) << 5);
        const float* wr_h = whh + (hh2 << 5);
        const float* wz_h = whh + ((hh2 + 32) << 5);
        const float* wn_h = whh + ((hh2 + 64) << 5);
        #pragma unroll
        for (int k = 0; k < 32; ++k) {
            rr = fmaf(wr_i[k], bg[k], rr);
            zz = fmaf(wz_i[k], bg[k], zz);
            an = fmaf(wn_i[k], bg[k], an);
            rr = fmaf(wr_h[k], cg[k], rr);
            zz = fmaf(wz_h[k], cg[k], zz);
            hn = fmaf(wn_h[k], cg[k], hn);
        }
        float r = 1.f / (1.f + __expf(-rr));
        float z = 1.f / (1.f + __expf(-zz));
        float e2 = __expf(2.f * fmaf(r, hn, an));
        float n = (e2 - 1.f) / (e2 + 1.f);
        ob[(size_t)((hh2 << 3) + gg) * NPIX_] = fmaf(z, cg[hh2] - n, n);
    }
}

// ---------------------------------------------------------------------------
extern "C" void kernel_launch(void* const* d_in, const int* in_sizes, int n_in,
                              void* d_out, int out_size, void* d_ws, size_t ws_size,
                              hipStream_t stream)
{
    const float* x   = (const float*)d_in[0];
    const float* Wc  = (const float*)d_in[1];
    const float* W0  = (const float*)d_in[2];
    const float* b0  = (const float*)d_in[3];
    const float* W1  = (const float*)d_in[4];
    const float* b1  = (const float*)d_in[5];
    const float* W2  = (const float*)d_in[6];
    const float* b2  = (const float*)d_in[7];
    const float* W3  = (const float*)d_in[8];
    const float* b3  = (const float*)d_in[9];
    const float* Wm  = (const float*)d_in[10];
    const float* Wih = (const float*)d_in[11];
    const float* Whh = (const float*)d_in[12];
    const float* bih = (const float*)d_in[13];
    const float* bhh = (const float*)d_in[14];
    float* out = (float*)d_out;

    float* p = (float*)d_ws;              // 4*1024*16 floats = 256 KB
    float* q = p + 4 * 1024 * 16;         // another 256 KB

    pool_kernel<<<1024, 256, 0, stream>>>(x, p);
    qmat_kernel<<<1024, 64, 0, stream>>>(p, q, W0, b0, W1, b1, W2, b2, W3, b3);
    fused_kernel<<<4096, 256, 0, stream>>>(x, q, Wc, Wm, Wih, Whh, bih, bhh, out);
}

// Round 3
// 360.404 us; speedup vs baseline: 3.3778x; 1.7153x over previous
//
#include <hip/hip_runtime.h>
#include <math.h>

#define B_    8
#define CIN_  128
#define H_    128
#define W_    128
#define NPIX_ 16384

typedef __attribute__((ext_vector_type(8))) short bf16x8;
typedef __attribute__((ext_vector_type(4))) float f32x4;

__device__ __forceinline__ short f2b(float f) {
    union { float f; unsigned u; } v; v.f = f;
    unsigned r = (v.u + 0x7FFF + ((v.u >> 16) & 1)) >> 16;   // RNE
    return (short)r;
}

// branch pool target sizes (h, w) and w-bin offsets into the 20-bin row table
__device__ __constant__ int c_oh[4]   = {1, 11, 3, 5};
__device__ __constant__ int c_ow[4]   = {11, 1, 5, 3};
__device__ __constant__ int c_woff[4] = {0, 11, 12, 17};

// ---------------------------------------------------------------------------
// Kernel 1: adaptive avg pool, single coalesced pass over x.
// p layout: p[(br*1024 + bc)*16 + (ih*ow+iw)]
// ---------------------------------------------------------------------------
__global__ __launch_bounds__(256) void pool_kernel(const float* __restrict__ x,
                                                   float* __restrict__ p)
{
    __shared__ float s_img[32][129];
    __shared__ float s_rb[128][20];

    int bc = blockIdx.x;               // b*128 + c
    const float* img = x + (size_t)bc * NPIX_;
    int t = threadIdx.x;

    for (int pass = 0; pass < 4; ++pass) {
        #pragma unroll
        for (int i = 0; i < 4; ++i) {
            int idx = t + i * 256;
            int rl = idx >> 5, c4 = idx & 31;
            float4 v = *(const float4*)(img + ((pass * 32 + rl) << 7) + (c4 << 2));
            s_img[rl][c4 * 4 + 0] = v.x;
            s_img[rl][c4 * 4 + 1] = v.y;
            s_img[rl][c4 * 4 + 2] = v.z;
            s_img[rl][c4 * 4 + 3] = v.w;
        }
        __syncthreads();
        for (int task = t; task < 640; task += 256) {
            int j = task >> 5, rl = task & 31;
            int br, iw;
            if (j < 11)      { br = 0; iw = j; }
            else if (j < 12) { br = 1; iw = 0; }
            else if (j < 17) { br = 2; iw = j - 12; }
            else             { br = 3; iw = j - 17; }
            int ow = c_ow[br];
            int ws = (iw * W_) / ow, we = ((iw + 1) * W_ + ow - 1) / ow;
            float s = 0.f;
            for (int c = ws; c < we; ++c) s += s_img[rl][c];
            s_rb[pass * 32 + rl][j] = s;
        }
        __syncthreads();
    }

    if (t < 52) {
        int br, loc;
        if (t < 11)      { br = 0; loc = t; }
        else if (t < 22) { br = 1; loc = t - 11; }
        else if (t < 37) { br = 2; loc = t - 22; }
        else             { br = 3; loc = t - 37; }
        int oh = c_oh[br], ow = c_ow[br];
        int ih = loc / ow, iw = loc % ow;
        int hs = (ih * H_) / oh, he = ((ih + 1) * H_ + oh - 1) / oh;
        int ws = (iw * W_) / ow, we = ((iw + 1) * W_ + ow - 1) / ow;
        int j = c_woff[br] + iw;
        float s = 0.f;
        for (int r = hs; r < he; ++r) s += s_rb[r][j];
        p[(br * 1024 + bc) * 16 + loc] = s / (float)((he - hs) * (we - ws));
    }
}

// ---------------------------------------------------------------------------
// Kernel 2: q[m] = sum_k Wl[m,k] * p[k] + bl[m]
// ---------------------------------------------------------------------------
__global__ void qmat_kernel(const float* __restrict__ p, float* __restrict__ q,
                            const float* __restrict__ W0, const float* __restrict__ b0,
                            const float* __restrict__ W1, const float* __restrict__ b1,
                            const float* __restrict__ W2, const float* __restrict__ b2,
                            const float* __restrict__ W3, const float* __restrict__ b3)
{
    int bc = blockIdx.x;
    int t = threadIdx.x;
    if (t >= 52) return;
    int br, m;
    if (t < 11)      { br = 0; m = t; }
    else if (t < 22) { br = 1; m = t - 11; }
    else if (t < 37) { br = 2; m = t - 22; }
    else             { br = 3; m = t - 37; }
    int cdim = (br < 2) ? 11 : 15;
    const float* Wl; const float* bl;
    if (br == 0)      { Wl = W0; bl = b0; }
    else if (br == 1) { Wl = W1; bl = b1; }
    else if (br == 2) { Wl = W2; bl = b2; }
    else              { Wl = W3; bl = b3; }
    const float* pr = p + (br * 1024 + bc) * 16;
    float acc = bl[m];
    for (int k = 0; k < cdim; ++k) acc += Wl[m * cdim + k] * pr[k];
    q[(br * 1024 + bc) * 16 + m] = acc;
}

// ---------------------------------------------------------------------------
// Kernel 3: Wih2[gg][96][64] = fold of merge conv into Wih
// bg[2gl+o] = sum_i Wm[16gg+gl][o][i] * a[4gl+i]
// ---------------------------------------------------------------------------
__global__ void fold_ih_kernel(const float* __restrict__ Wih,
                               const float* __restrict__ Wm,
                               float* __restrict__ Wih2)
{
    int gg = blockIdx.x, t = threadIdx.x;
    for (int idx = t; idx < 6144; idx += 256) {
        int r = idx >> 6, c = idx & 63;
        int gl = c >> 2, i = c & 3;
        float s = Wih[gg * 3072 + r * 32 + 2 * gl]     * Wm[(16 * gg + gl) * 8 + i]
                + Wih[gg * 3072 + r * 32 + 2 * gl + 1] * Wm[(16 * gg + gl) * 8 + 4 + i];
        Wih2[gg * 6144 + idx] = s;
    }
}

// ---------------------------------------------------------------------------
// Kernel 4: M1[b][gg][96][16] = Wih2[gg] @ qg[b][gg]  + bih (col-sum(T)=1 fold)
// ---------------------------------------------------------------------------
__global__ void fold_m1_kernel(const float* __restrict__ Wih2,
                               const float* __restrict__ q,
                               const float* __restrict__ bih,
                               unsigned short* __restrict__ M1)
{
    int bgg = blockIdx.x;               // b*8 + gg
    int b = bgg >> 3, gg = bgg & 7;
    int t = threadIdx.x;
    int br = gg >> 1, chb = (gg & 1) * 64;
    const float* qbase = q + (size_t)((br * 1024 + b * 128 + chb) << 4);
    for (int idx = t; idx < 1536; idx += 256) {
        int r = idx >> 4, bin = idx & 15;
        float s = bih[gg * 96 + r];
        const float* w = Wih2 + gg * 6144 + r * 64;
        for (int c = 0; c < 64; ++c) s += w[c] * qbase[c * 16 + bin];
        M1[(size_t)(bgg * 96 + r) * 16 + bin] = (unsigned short)f2b(s);
    }
}

// ---------------------------------------------------------------------------
// Kernel 5: M2[gg][128][32]: rows 0-95 = Whh@Wc (K=32), col16 = bhh;
//           rows 96-127 = Wc, col16 = 0; cols 17-31 = 0.
// ---------------------------------------------------------------------------
__global__ void fold_m2_kernel(const float* __restrict__ Whh,
                               const float* __restrict__ Wc,
                               const float* __restrict__ bhh,
                               unsigned short* __restrict__ M2)
{
    int gg = blockIdx.x, t = threadIdx.x;
    for (int idx = t; idx < 4096; idx += 256) {
        int r = idx >> 5, c = idx & 31;
        float v = 0.f;
        if (r < 96) {
            if (c < 16) {
                for (int h = 0; h < 32; ++h)
                    v += Whh[gg * 3072 + r * 32 + h] * Wc[gg * 512 + h * 16 + c];
            } else if (c == 16) v = bhh[gg * 96 + r];
        } else {
            if (c < 16) v = Wc[gg * 512 + (r - 96) * 16 + c];
        }
        M2[(size_t)(gg * 128 + r) * 32 + c] = (unsigned short)f2b(v);
    }
}

// ---------------------------------------------------------------------------
// Kernel 6: fused MFMA: gates_i = M1 @ T, [gates_h; cg] = M2 @ [x;1;0...],
// then GRU nonlinearity per pixel. One block = (b, gg, 1024-px tile).
// ---------------------------------------------------------------------------
template<int OH, int OW>
__device__ __forceinline__ void fused_body(
    const float* __restrict__ x, const unsigned short* __restrict__ M1,
    const unsigned short* __restrict__ M2, float* __restrict__ out,
    int b, int gg, int tile, int tid)
{
    int lane = tid & 63, wv = tid >> 6;
    int col = lane & 15, quad = lane >> 4;

    // ---- A fragments (row = lane&15, k = quad*8+j)
    bf16x8 m1f[6], m2f[8];
    const unsigned short* m1b = M1 + (size_t)(b * 8 + gg) * 96 * 16;
    #pragma unroll
    for (int t = 0; t < 6; ++t) {
        if (quad < 2) m1f[t] = *(const bf16x8*)(m1b + (t * 16 + col) * 16 + quad * 8);
        else          m1f[t] = bf16x8{0, 0, 0, 0, 0, 0, 0, 0};
    }
    const unsigned short* m2b = M2 + (size_t)gg * 128 * 32;
    #pragma unroll
    for (int t = 0; t < 8; ++t)
        m2f[t] = *(const bf16x8*)(m2b + (t * 16 + col) * 32 + quad * 8);

    const float* xb = x + (size_t)(b * 128 + gg * 16) * NPIX_;
    float* ob = out + (size_t)b * 256 * NPIX_;
    int waveBase = tile * 1024 + wv * 256;

    #pragma unroll 2
    for (int n = 0; n < 16; ++n) {
        int ntBase = waveBase + n * 16;
        int hPix = ntBase >> 7, w0 = ntBase & 127;
        int w = w0 + col;

        // ---- bilinear taps: h side wave-uniform, w side per-lane
        int i0h = 0; float fh = 0.f;
        if (OH > 1) {
            float src = (float)(hPix * (OH - 1)) * (1.f / 127.f);
            i0h = (int)src;
            if (i0h > OH - 2) i0h = OH - 2;
            fh = src - (float)i0h;
        }
        int i1h = (OH > 1) ? i0h + 1 : 0;
        float wh0 = 1.f - fh, wh1 = fh;
        int i0w = 0; float fw = 0.f;
        if (OW > 1) {
            float srcw = (float)(w * (OW - 1)) * (1.f / 127.f);
            i0w = (int)srcw;
            if (i0w > OW - 2) i0w = OW - 2;
            fw = srcw - (float)i0w;
        }
        int i1w = (OW > 1) ? i0w + 1 : 0;
        float ww0 = 1.f - fw, ww1 = fw;

        // ---- B fragment: T (col = pixel, k = bin)
        bf16x8 tf = bf16x8{0, 0, 0, 0, 0, 0, 0, 0};
        if (quad < 2) {
            int kbase = quad * 8;
            #pragma unroll
            for (int j = 0; j < 8; ++j) {
                int k = kbase + j;
                int ih = k / OW, iw = k - ih * OW;   // div by literal
                float hf = (ih == i0h) ? wh0 : ((ih == i1h) ? wh1 : 0.f);
                float wf = (iw == i0w) ? ww0 : ((iw == i1w) ? ww1 : 0.f);
                tf[j] = f2b(hf * wf);
            }
        }

        // ---- B fragment: [x ; 1 ; 0]
        bf16x8 xf = bf16x8{0, 0, 0, 0, 0, 0, 0, 0};
        if (quad < 2) {
            const float* xp = xb + (size_t)(quad * 8) * NPIX_ + ntBase + col;
            #pragma unroll
            for (int j = 0; j < 8; ++j) xf[j] = f2b(xp[(size_t)j * NPIX_]);
        } else if (quad == 2) {
            xf[0] = (short)0x3F80;   // bf16 1.0 in k==16 (ones row -> bhh)
        }

        // ---- MFMAs
        f32x4 a1[6], a2[8];
        #pragma unroll
        for (int t = 0; t < 6; ++t) a1[t] = f32x4{0.f, 0.f, 0.f, 0.f};
        #pragma unroll
        for (int t = 0; t < 8; ++t) a2[t] = f32x4{0.f, 0.f, 0.f, 0.f};
        #pragma unroll
        for (int t = 0; t < 6; ++t)
            a1[t] = __builtin_amdgcn_mfma_f32_16x16x32_bf16(m1f[t], tf, a1[t], 0, 0, 0);
        #pragma unroll
        for (int t = 0; t < 8; ++t)
            a2[t] = __builtin_amdgcn_mfma_f32_16x16x32_bf16(m2f[t], xf, a2[t], 0, 0, 0);

        // ---- GRU nonlinearity + store (C: col = lane&15, row = quad*4+reg)
        float* op = ob + ntBase + col;
        #pragma unroll
        for (int a = 0; a < 2; ++a) {
            #pragma unroll
            for (int r = 0; r < 4; ++r) {
                float ir  = a1[a][r]     + a2[a][r];
                float iz  = a1[2 + a][r] + a2[2 + a][r];
                float in_ = a1[4 + a][r];
                float hn  = a2[4 + a][r];
                float cgv = a2[6 + a][r];
                float rg = 1.f / (1.f + __expf(-ir));
                float zg = 1.f / (1.f + __expf(-iz));
                float e2 = __expf(2.f * fmaf(rg, hn, in_));
                float nn = (e2 - 1.f) / (e2 + 1.f);
                float y  = fmaf(zg, cgv - nn, nn);
                int h = a * 16 + quad * 4 + r;
                op[(size_t)((h << 3) + gg) * NPIX_] = y;
            }
        }
    }
}

__global__ __launch_bounds__(256) void fused_mfma_kernel(
    const float* __restrict__ x, const unsigned short* __restrict__ M1,
    const unsigned short* __restrict__ M2, float* __restrict__ out)
{
    int bid = blockIdx.x;
    int tile = bid & 15, gg = (bid >> 4) & 7, b = bid >> 7;
    switch (gg >> 1) {
        case 0: fused_body<1, 11>(x, M1, M2, out, b, gg, tile, threadIdx.x); break;
        case 1: fused_body<11, 1>(x, M1, M2, out, b, gg, tile, threadIdx.x); break;
        case 2: fused_body<3, 5>(x, M1, M2, out, b, gg, tile, threadIdx.x); break;
        default: fused_body<5, 3>(x, M1, M2, out, b, gg, tile, threadIdx.x); break;
    }
}

// ---------------------------------------------------------------------------
extern "C" void kernel_launch(void* const* d_in, const int* in_sizes, int n_in,
                              void* d_out, int out_size, void* d_ws, size_t ws_size,
                              hipStream_t stream)
{
    const float* x   = (const float*)d_in[0];
    const float* Wc  = (const float*)d_in[1];
    const float* W0  = (const float*)d_in[2];
    const float* b0  = (const float*)d_in[3];
    const float* W1  = (const float*)d_in[4];
    const float* b1  = (const float*)d_in[5];
    const float* W2  = (const float*)d_in[6];
    const float* b2  = (const float*)d_in[7];
    const float* W3  = (const float*)d_in[8];
    const float* b3  = (const float*)d_in[9];
    const float* Wm  = (const float*)d_in[10];
    const float* Wih = (const float*)d_in[11];
    const float* Whh = (const float*)d_in[12];
    const float* bih = (const float*)d_in[13];
    const float* bhh = (const float*)d_in[14];
    float* out = (float*)d_out;

    // workspace layout (bytes):
    //   p    : 0        .. 262144   (65536 f32)
    //   q    : 262144   .. 524288   (65536 f32)
    //   Wih2 : 524288   .. 720896   (49152 f32)
    //   M1   : 720896   .. 917504   (98304 bf16)
    //   M2   : 917504   .. 983040   (32768 bf16)
    char* ws = (char*)d_ws;
    float* p            = (float*)(ws + 0);
    float* q            = (float*)(ws + 262144);
    float* Wih2         = (float*)(ws + 524288);
    unsigned short* M1  = (unsigned short*)(ws + 720896);
    unsigned short* M2  = (unsigned short*)(ws + 917504);

    pool_kernel<<<1024, 256, 0, stream>>>(x, p);
    qmat_kernel<<<1024, 64, 0, stream>>>(p, q, W0, b0, W1, b1, W2, b2, W3, b3);
    fold_ih_kernel<<<8, 256, 0, stream>>>(Wih, Wm, Wih2);
    fold_m1_kernel<<<64, 256, 0, stream>>>(Wih2, q, bih, M1);
    fold_m2_kernel<<<8, 256, 0, stream>>>(Whh, Wc, bhh, M2);
    fused_mfma_kernel<<<1024, 256, 0, stream>>>(x, M1, M2, out);
}